// Round 15
// baseline (135.577 us; speedup 1.0000x reference)
//
#include <hip/hip_runtime.h>
#include <math.h>

// Problem constants
#define D 64
#define K 512
#define NROWS 65536
#define DECAY 0.99f
#define ONE_MINUS_DECAY (1.0f - 0.99f)
#define COMMIT 0.25f

// ws layout (float offsets).  Pipeline: prep -> main -> scatter -> dwsum ->
// final.  r15: vq_main phase widened 1 tile -> 4 tiles (barriers 16 -> 4+1,
// LDS 16 KB -> 64 KB double buffer; grid already caps at 2 blocks/CU so the
// LDS growth is free).  Staging cadence (2 loads per tile-compute) unchanged.
#define WS_DWT    0              // [K][D] = 32768 floats, dw accumulator (zeroed)
#define WS_CNT    32768          // [K] ints (written by scatter blk0)
#define WS_LPART  33280          // [2048] floats, per-wave loss (plain stores)
#define WS_ZERO4  8192           // float4 count zeroed by prep (= dw_t only)
#define WS_ESQ    35328          // [K]   ||e_k||^2
#define WS_ET     35840          // [K][D] fp32 embeddings transposed (gather)
#define WS_EF     68608          // f16 MFMA B-fragments: 8192 x 16B = 32768 floats
#define WS_IDX    101376         // [N] int indices
#define WS_HIST   166912         // [64][K] ints per-scatter-block histograms
#define WS_PERM   35840          // [N] int (row<<9 | k) — ALIASES ET+EF (dead
                                 // after vq_main; scatter runs later)

// out layout (float offsets) — unchanged
#define OUT_Q     0
#define OUT_LOSS  4194304
#define OUT_PERP  4194305
#define OUT_IDX   4194306
#define OUT_NEMB  4259842
#define OUT_HCS   4292610
#define OUT_HDW   4293122

typedef _Float16 f16x8 __attribute__((ext_vector_type(8)));
typedef float    f32x16 __attribute__((ext_vector_type(16)));

// ---------------- prep: zero dw_t + hist64 + e_t + ||e||^2 + f16 fragments ---
// B-fragment layout for v_mfma_f32_32x32x16_f16:
//   lane l supplies col = tile*32 + (l&31), k = (l>>5)*8 + j (j=0..7)
// fragment block index i = ((t*4 + s)*2 + h)*64 + l  (s=kstep, h=0 hi / 1 lo)
__global__ void vq_prep(const float* __restrict__ emb,  // [D][K]
                        float* __restrict__ ws)
{
    int i = blockIdx.x * 256 + threadIdx.x;   // 0..32767 (128 blocks)
    if (i < WS_ZERO4) {                       // zero dw_t
        ((float4*)ws)[i] = make_float4(0.f, 0.f, 0.f, 0.f);
    }
    ((int*)(ws + WS_HIST))[i] = 0;            // zero hist64 (exactly 32768 ints)
    if (i < K * D) {                          // e_t[k][d] = emb[d][k]
        int k = i >> 6, d = i & 63;
        ws[WS_ET + i] = emb[d * K + k];
    }
    if (i < K) {                              // ||e_k||^2
        float s = 0.f;
        for (int d = 0; d < D; ++d) { float v = emb[d * K + i]; s += v * v; }
        ws[WS_ESQ + i] = s;
    }
    if (i < 8192) {                           // f16 hi/lo fragment buffer
        int l = i & 63, h = (i >> 6) & 1, s = (i >> 7) & 3, t = i >> 9;
        int col = t * 32 + (l & 31);
        int d0  = s * 16 + ((l >> 5) << 3);
        f16x8 frag;
#pragma unroll
        for (int j = 0; j < 8; ++j) {
            float v = emb[(d0 + j) * K + col];
            _Float16 hv = (_Float16)v;
            frag[j] = h ? (_Float16)(v - (float)hv) : hv;
        }
        ((f16x8*)(ws + WS_EF))[i] = frag;
    }
}

// ---------------- main: full-K/wave, 4-tile LDS phases, fused histogram ------
// 512 blocks x 4 waves; wave w owns rows blockIdx*128+w*32..+31, scans ALL
// 512 codes.  B shared via a 2x4-tile (64 KB) LDS double buffer: while
// computing tile 4p+j from ebuf[cur][j], each wave loads its 2 fragments of
// tile 4(p+1)+j and writes them to ebuf[cur^1][j].  ONE barrier per phase
// (4 total vs r14's 16) both publishes the next phase and retires reads of
// the current one.  Staging register load = 2 f16x8 (unchanged from r14 —
// no spill-pressure change).
// Argmin key = (monotone(score_bits)<<32) | k: u64 min == (min score, min k).
// Loss identity: sum((q-x)^2) = sum_rows(||x||^2 + best_score).
// C/D layout: col = lane&31, row = (reg&3) + 8*(reg>>2) + 4*(lane>>5).
__global__ __launch_bounds__(256, 4)
void vq_main(const float* __restrict__ x,     // [N][D]
             const float* __restrict__ e_sq,  // [K]
             const float* __restrict__ e_t,   // [K][D] fp32
             const float* __restrict__ ef,    // f16 fragment buffer
             float* __restrict__ out_q,       // [N][D]
             float* __restrict__ out_idx,     // [N] (float)
             int*   __restrict__ idxN,        // [N] int indices
             int*   __restrict__ hist64,      // [64][K] accumulate
             float* __restrict__ lparts)      // [2048] per-wave loss
{
    __shared__ f16x8 ebuf[2][4][8][64];       // 64 KB double-buffered 4-tile B
    __shared__ int   idx_s[4][32];
    __shared__ int   h[K];

    const int tid  = threadIdx.x;
    const int w    = tid >> 6;
    const int l    = tid & 63;
    const int lr   = l & 31;       // A-row / B-col / C-col within tile
    const int hb   = l >> 5;       // k-group select
    const int row0 = blockIdx.x * 128 + w * 32;   // wave-private rows

    h[tid] = 0; h[tid + 256] = 0;  // published by the prologue barrier

    // ---- A fragments: lane supplies row (row0+lr), k = s*16 + hb*8 + j.
    f16x8 ah[4], al[4];
    float xsq = 0.f;
    {
        const float* xr = x + (size_t)(row0 + lr) * D + hb * 8;
#pragma unroll
        for (int s = 0; s < 4; ++s) {
            float4 f0 = *(const float4*)(xr + s * 16);
            float4 f1 = *(const float4*)(xr + s * 16 + 4);
            float f[8] = {f0.x, f0.y, f0.z, f0.w, f1.x, f1.y, f1.z, f1.w};
#pragma unroll
            for (int j = 0; j < 8; ++j) {
                xsq = fmaf(f[j], f[j], xsq);
                _Float16 hv = (_Float16)f[j];
                ah[s][j] = hv;
                al[s][j] = (_Float16)(f[j] - (float)hv);
            }
        }
    }

    float    best[16];
    unsigned packlo = 0u, packhi = 0u;   // 4-bit best-tile (tt) per acc reg
#pragma unroll
    for (int r = 0; r < 16; ++r) best[r] = 3.0e38f;

    const f16x8* __restrict__ efv = (const f16x8*)ef;
    const int f0 = 2 * w;                // this wave's staging fragments

    // ---- prologue: stage phase 0 (tiles 0..3), load->write pairs -----------
#pragma unroll
    for (int j = 0; j < 4; ++j) {
        ebuf[0][j][f0 + 0][l] = efv[(j * 8 + f0 + 0) * 64 + l];
        ebuf[0][j][f0 + 1][l] = efv[(j * 8 + f0 + 1) * 64 + l];
    }
    __syncthreads();

    int cur = 0;
    for (int ph = 0; ph < 4; ++ph) {
#pragma unroll
        for (int j = 0; j < 4; ++j) {
            const int tt = ph * 4 + j;
            // issue next-phase loads first (latency hides under this compute)
            f16x8 st0, st1;
            if (ph < 3) {
                st0 = efv[((tt + 4) * 8 + f0 + 0) * 64 + l];
                st1 = efv[((tt + 4) * 8 + f0 + 1) * 64 + l];
            }

            // compute tile tt from ebuf[cur][j]
            f32x16 acc = {};
#pragma unroll
            for (int s = 0; s < 4; ++s) {
                f16x8 bh = ebuf[cur][j][s * 2 + 0][l];
                f16x8 bl = ebuf[cur][j][s * 2 + 1][l];
                acc = __builtin_amdgcn_mfma_f32_32x32x16_f16(al[s], bh, acc, 0, 0, 0);
                acc = __builtin_amdgcn_mfma_f32_32x32x16_f16(ah[s], bl, acc, 0, 0, 0);
                acc = __builtin_amdgcn_mfma_f32_32x32x16_f16(ah[s], bh, acc, 0, 0, 0);
            }

            const float eq = e_sq[tt * 32 + lr];
#pragma unroll
            for (int r = 0; r < 16; ++r) {
                float sc = fmaf(-2.0f, acc[r], eq);
                bool better = sc < best[r];      // strict: earliest tt wins ties
                best[r] = better ? sc : best[r]; // == v_min_f32
                if (r < 8) {
                    unsigned nb = (packlo & ~(15u << (4 * r)))
                                | ((unsigned)tt << (4 * r));
                    packlo = better ? nb : packlo;
                } else {
                    unsigned nb = (packhi & ~(15u << (4 * (r - 8))))
                                | ((unsigned)tt << (4 * (r - 8)));
                    packhi = better ? nb : packhi;
                }
            }

            // write next-phase tile j into the other buffer
            if (ph < 3) {
                ebuf[cur ^ 1][j][f0 + 0][l] = st0;
                ebuf[cur ^ 1][j][f0 + 1][l] = st1;
            }
        }
        // ONE barrier per phase: publishes ebuf[cur^1], retires ebuf[cur] reads
        __syncthreads();
        cur ^= 1;
    }

    // ---- per-row argmin across the 32 lanes of each half: u64-key butterfly.
    float sum_best = 0.f;
#pragma unroll
    for (int r = 0; r < 16; ++r) {
        unsigned tt4 = ((r < 8) ? (packlo >> (4 * r))
                                : (packhi >> (4 * (r - 8)))) & 15u;
        int bk = ((int)tt4 << 5) | lr;
        unsigned sb = __float_as_uint(best[r]);
        sb ^= (unsigned)((int)sb >> 31) | 0x80000000u;   // monotone transform
        unsigned long long key =
            ((unsigned long long)sb << 32) | (unsigned)bk;
#pragma unroll
        for (int m = 16; m >= 1; m >>= 1) {
            unsigned long long o = __shfl_xor(key, m, 64);
            key = (o < key) ? o : key;
        }
        unsigned wb = (unsigned)(key >> 32);
        wb ^= ~(unsigned)((int)wb >> 31) | 0x80000000u;  // inverse transform
        sum_best += __uint_as_float(wb);
        if (lr == 0) {
            int ro = (r & 3) + 8 * (r >> 2) + 4 * hb;
            idx_s[w][ro] = (int)(key & 511u);
        }
    }
    // same-wave LDS write->read below: compiler inserts lgkmcnt, no barrier.

    // ---- loss: Sigma rows ||x||^2 (all 64 lane-halves) + Sigma best --------
    {
        float xs = xsq;
#pragma unroll
        for (int m = 32; m >= 1; m >>= 1) xs += __shfl_xor(xs, m, 64);
        float tb = sum_best + __shfl_xor(sum_best, 32, 64); // hb0 + hb1 sums
        if (l == 0)
            lparts[blockIdx.x * 4 + w] = xs + tb;           // plain store
    }

    // ---- indices + gather + out_q (wave-private, row-contiguous) -----------
    if (l < 32) {
        int bk = idx_s[w][l];
        out_idx[row0 + l] = (float)bk;
        idxN[row0 + l]    = bk;
    }
#pragma unroll
    for (int rr = 0; rr < 32; ++rr) {
        const int kk = idx_s[w][rr];
        out_q[(size_t)(row0 + rr) * D + l] = e_t[kk * D + l];
    }

    // ---- fused histogram: LDS count of this block's 128 rows, then sparse
    // global accumulate into hist64[blockIdx>>3][k] (replaces vq_hist).
    __syncthreads();                           // all idx_s final
    if (tid < 128)
        atomicAdd(&h[idx_s[tid >> 5][tid & 31]], 1);
    __syncthreads();
    int* hrow = hist64 + (blockIdx.x >> 3) * K;
    int v0 = h[tid], v1 = h[tid + 256];
    if (v0) atomicAdd(&hrow[tid], v0);
    if (v1) atomicAdd(&hrow[tid + 256], v1);
}

// ---------------- scatter: redundant scan + deterministic perm ---------------
// 64 blocks x 512.  Each block column-scans hist64 (64 iters) capturing its
// own base, Hillis-Steele over k for global offsets, then scatters its 1024
// rows via LDS counters.  Zero global atomics.  Block 0 publishes cnt[k].
__global__ __launch_bounds__(512)
void vq_scatter(const int* __restrict__ hist,  // [64][K]
                const int* __restrict__ idxN,  // [N]
                int* __restrict__ cnt,         // [K]
                int* __restrict__ perm)        // [N] (row<<9 | k), k-sorted
{
    __shared__ int s[K];

    const int t = threadIdx.x;            // 0..511
    const int b = blockIdx.x;

    int run = 0, mybase = 0;
    for (int b2 = 0; b2 < 64; ++b2) {     // column scan of hist[:, t]
        int h = hist[b2 * K + t];
        if (b2 == b) mybase = run;
        run += h;
    }
    if (b == 0) cnt[t] = run;             // total per bin

    s[t] = run;
    __syncthreads();
#pragma unroll
    for (int off = 1; off < K; off <<= 1) {   // inclusive scan of totals
        int v = (t >= off) ? s[t - off] : 0;
        __syncthreads();
        s[t] += v;
        __syncthreads();
    }
    const int offs = s[t] - run;          // exclusive prefix
    __syncthreads();
    s[t] = offs + mybase;                 // this block's start for bin t
    __syncthreads();

#pragma unroll
    for (int it = 0; it < 2; ++it) {
        int row = b * 1024 + it * 512 + t;
        int kk  = idxN[row];
        int pos = atomicAdd(&s[kk], 1);   // LDS atomic (block-local)
        perm[pos] = (row << 9) | kk;
    }
}

// ---------------- dw segmented reduce over k-sorted perm ---------------------
// 512 blocks x 256 = 2048 waves; wave w owns perm chunk [32w, 32w+32).
// lane = d.  k is wave-uniform per entry -> flush only at run boundaries.
__global__ __launch_bounds__(256, 2)
void vq_dwsum(const int* __restrict__ perm,  // [N] (row<<9 | k)
              const float* __restrict__ x,   // [N][D]
              float* __restrict__ dw_t)      // [K][D] accumulate
{
    const int w = (blockIdx.x * 256 + threadIdx.x) >> 6;  // 0..2047
    const int l = threadIdx.x & 63;

    int pv = 0;
    if (l < 32) pv = perm[w * 32 + l];

    float sum = 0.f;
    int kcur = -1;
#pragma unroll
    for (int e = 0; e < 32; ++e) {
        int pe  = __shfl(pv, e, 64);
        int kk  = pe & (K - 1);
        int row = pe >> 9;
        float xv = x[(size_t)row * D + l];
        if (kk != kcur) {                       // wave-uniform branch
            if (kcur >= 0) atomicAdd(&dw_t[kcur * D + l], sum);
            kcur = kk; sum = xv;
        } else {
            sum += xv;
        }
    }
    atomicAdd(&dw_t[kcur * D + l], sum);
}

// ---------------- finalize: scalars + hdw + new embeddings -------------------
// 128 blocks x 256.  Every block redundantly recomputes debias and the
// n-reduction from cnt (2KB, L2-resident).
__global__ __launch_bounds__(256)
void vq_final(const int*   __restrict__ cnt,     // [K]
              const float* __restrict__ lparts,  // [2048] per-wave loss
              const float* __restrict__ ema_csh, // [K]
              const int*   __restrict__ counter,
              const float* __restrict__ ema_dwh, // [D][K]
              const float* __restrict__ dw_t,    // [K][D]
              float* __restrict__ out_loss,
              float* __restrict__ out_perp,
              float* __restrict__ out_hcs,       // [K]
              float* __restrict__ out_nemb,      // [D][K]
              float* __restrict__ out_hdw)       // [D][K]
{
    __shared__ float s_red[4], s_red2[4];
    __shared__ float s_n;

    const int tid = threadIdx.x;
    const int b   = blockIdx.x;

    const int   cntr   = counter[0] + 1;
    const float debias = 1.0f - powf(DECAY, (float)cntr);

    const float c0 = (float)cnt[tid];
    const float c1 = (float)cnt[tid + 256];
    const float hid0 = ema_csh[tid] * DECAY + c0 * ONE_MINUS_DECAY;
    const float hid1 = ema_csh[tid + 256] * DECAY + c1 * ONE_MINUS_DECAY;
    const float upd0 = hid0 / debias;
    const float upd1 = hid1 / debias;

    float v = upd0 + upd1;
#pragma unroll
    for (int m = 32; m >= 1; m >>= 1) v += __shfl_xor(v, m, 64);
    if ((tid & 63) == 0) s_red[tid >> 6] = v;
    __syncthreads();
    if (tid == 0) s_n = s_red[0] + s_red[1] + s_red[2] + s_red[3];
    __syncthreads();
    const float n = s_n;

    const int i  = b * 256 + tid;          // 0..32767
    const int kk = i & (K - 1);
    const int d  = i >> 9;
    const float updk   = (b & 1) ? upd1 : upd0;
    const float stable = (updk + 1e-5f) / (n + (float)K * 1e-5f) * n;
    const float hdw = ema_dwh[i] * DECAY + dw_t[kk * D + d] * ONE_MINUS_DECAY;
    out_hdw[i]  = hdw;
    out_nemb[i] = (hdw / debias) / stable;

    if (b == 0) {
        out_hcs[tid]       = hid0;
        out_hcs[tid + 256] = hid1;

        const float inv = 1.0f / (float)NROWS;
        float p0 = c0 * inv, p1 = c1 * inv;
        float ve = p0 * logf(p0 + 1e-10f) + p1 * logf(p1 + 1e-10f);
        float lp = 0.f;
#pragma unroll
        for (int j = 0; j < 8; ++j) lp += lparts[tid + 256 * j];
#pragma unroll
        for (int m = 32; m >= 1; m >>= 1) {
            ve += __shfl_xor(ve, m, 64);
            lp += __shfl_xor(lp, m, 64);
        }
        __syncthreads();                    // safe re-use of s_red
        if ((tid & 63) == 0) { s_red[tid >> 6] = ve; s_red2[tid >> 6] = lp; }
        __syncthreads();
        if (tid == 0) {
            float e = s_red[0] + s_red[1] + s_red[2] + s_red[3];
            float L = s_red2[0] + s_red2[1] + s_red2[2] + s_red2[3];
            out_loss[0] = COMMIT * L / (float)((size_t)NROWS * D);
            out_perp[0] = expf(-e);
        }
    }
}

// ---------------- launch ------------------------------------------------------
extern "C" void kernel_launch(void* const* d_in, const int* in_sizes, int n_in,
                              void* d_out, int out_size, void* d_ws, size_t ws_size,
                              hipStream_t stream)
{
    const float* x_in    = (const float*)d_in[0];   // [64,32,32,64]
    const float* emb     = (const float*)d_in[1];   // [64,512]
    const float* ema_csh = (const float*)d_in[2];   // [512]
    const float* ema_dwh = (const float*)d_in[3];   // [64,512]
    const int*   counter = (const int*)d_in[4];     // [1]

    float* ws  = (float*)d_ws;
    float* out = (float*)d_out;

    vq_prep<<<128, 256, 0, stream>>>(emb, ws);

    vq_main<<<NROWS / 128, 256, 0, stream>>>(
        x_in, ws + WS_ESQ, ws + WS_ET, ws + WS_EF,
        out + OUT_Q, out + OUT_IDX,
        (int*)(ws + WS_IDX), (int*)(ws + WS_HIST), ws + WS_LPART);

    vq_scatter<<<64, 512, 0, stream>>>(
        (const int*)(ws + WS_HIST), (const int*)(ws + WS_IDX),
        (int*)(ws + WS_CNT), (int*)(ws + WS_PERM));

    vq_dwsum<<<512, 256, 0, stream>>>(
        (const int*)(ws + WS_PERM), x_in, ws + WS_DWT);

    vq_final<<<128, 256, 0, stream>>>(
        (const int*)(ws + WS_CNT), ws + WS_LPART, ema_csh, counter,
        ema_dwh, ws + WS_DWT,
        out + OUT_LOSS, out + OUT_PERP, out + OUT_HCS,
        out + OUT_NEMB, out + OUT_HDW);
}

// Round 16
// 117.442 us; speedup vs baseline: 1.1544x; 1.1544x over previous
//
#include <hip/hip_runtime.h>
#include <math.h>

// Problem constants
#define D 64
#define K 512
#define NROWS 65536
#define DECAY 0.99f
#define ONE_MINUS_DECAY (1.0f - 0.99f)
#define COMMIT 0.25f

// ws layout (float offsets).  Pipeline: prep -> main -> scatter -> dwsum ->
// final.  r16 = r14 revert (r15's 4-tile phase blew VGPR 64->228, occ 36->9%)
// + dwsum at 16 entries/wave (4096 waves, 2x latency-hiding pool).
#define WS_DWT    0              // [K][D] = 32768 floats, dw accumulator (zeroed)
#define WS_CNT    32768          // [K] ints (written by scatter blk0)
#define WS_LPART  33280          // [2048] floats, per-wave loss (plain stores)
#define WS_ZERO4  8192           // float4 count zeroed by prep (= dw_t only)
#define WS_ESQ    35328          // [K]   ||e_k||^2
#define WS_ET     35840          // [K][D] fp32 embeddings transposed (gather)
#define WS_EF     68608          // f16 MFMA B-fragments: 8192 x 16B = 32768 floats
#define WS_IDX    101376         // [N] int indices
#define WS_HIST   166912         // [64][K] ints per-scatter-block histograms
#define WS_PERM   35840          // [N] int (row<<9 | k) — ALIASES ET+EF (dead
                                 // after vq_main; scatter runs later)

// out layout (float offsets) — unchanged
#define OUT_Q     0
#define OUT_LOSS  4194304
#define OUT_PERP  4194305
#define OUT_IDX   4194306
#define OUT_NEMB  4259842
#define OUT_HCS   4292610
#define OUT_HDW   4293122

typedef _Float16 f16x8 __attribute__((ext_vector_type(8)));
typedef float    f32x16 __attribute__((ext_vector_type(16)));

// ---------------- prep: zero dw_t + hist64 + e_t + ||e||^2 + f16 fragments ---
// B-fragment layout for v_mfma_f32_32x32x16_f16:
//   lane l supplies col = tile*32 + (l&31), k = (l>>5)*8 + j (j=0..7)
// fragment block index i = ((t*4 + s)*2 + h)*64 + l  (s=kstep, h=0 hi / 1 lo)
__global__ void vq_prep(const float* __restrict__ emb,  // [D][K]
                        float* __restrict__ ws)
{
    int i = blockIdx.x * 256 + threadIdx.x;   // 0..32767 (128 blocks)
    if (i < WS_ZERO4) {                       // zero dw_t
        ((float4*)ws)[i] = make_float4(0.f, 0.f, 0.f, 0.f);
    }
    ((int*)(ws + WS_HIST))[i] = 0;            // zero hist64 (exactly 32768 ints)
    if (i < K * D) {                          // e_t[k][d] = emb[d][k]
        int k = i >> 6, d = i & 63;
        ws[WS_ET + i] = emb[d * K + k];
    }
    if (i < K) {                              // ||e_k||^2
        float s = 0.f;
        for (int d = 0; d < D; ++d) { float v = emb[d * K + i]; s += v * v; }
        ws[WS_ESQ + i] = s;
    }
    if (i < 8192) {                           // f16 hi/lo fragment buffer
        int l = i & 63, h = (i >> 6) & 1, s = (i >> 7) & 3, t = i >> 9;
        int col = t * 32 + (l & 31);
        int d0  = s * 16 + ((l >> 5) << 3);
        f16x8 frag;
#pragma unroll
        for (int j = 0; j < 8; ++j) {
            float v = emb[(d0 + j) * K + col];
            _Float16 hv = (_Float16)v;
            frag[j] = h ? (_Float16)(v - (float)hv) : hv;
        }
        ((f16x8*)(ws + WS_EF))[i] = frag;
    }
}

// ---------------- main: full-K/wave + LDS dbuf B + fused histogram -----------
// (byte-identical to r14's verified 121.7us vq_main)
// 512 blocks x 4 waves; wave w owns rows blockIdx*128+w*32..+31, scans ALL
// 512 codes.  B-tile shared via 16KB LDS double buffer; 2 staging fragments
// live per wave (r15 showed 4-tile phases blow this to 8 -> VGPR 228).
// Argmin key = (monotone(score_bits)<<32) | k: u64 min == (min score, min k).
// Loss identity: sum((q-x)^2) = sum_rows(||x||^2 + best_score).
// C/D layout: col = lane&31, row = (reg&3) + 8*(reg>>2) + 4*(lane>>5).
__global__ __launch_bounds__(256, 4)
void vq_main(const float* __restrict__ x,     // [N][D]
             const float* __restrict__ e_sq,  // [K]
             const float* __restrict__ e_t,   // [K][D] fp32
             const float* __restrict__ ef,    // f16 fragment buffer
             float* __restrict__ out_q,       // [N][D]
             float* __restrict__ out_idx,     // [N] (float)
             int*   __restrict__ idxN,        // [N] int indices
             int*   __restrict__ hist64,      // [64][K] accumulate
             float* __restrict__ lparts)      // [2048] per-wave loss
{
    __shared__ f16x8 ebuf[2][8][64];          // 16 KB double-buffered B tile
    __shared__ int   idx_s[4][32];
    __shared__ int   h[K];

    const int tid  = threadIdx.x;
    const int w    = tid >> 6;
    const int l    = tid & 63;
    const int lr   = l & 31;       // A-row / B-col / C-col within tile
    const int hb   = l >> 5;       // k-group select
    const int row0 = blockIdx.x * 128 + w * 32;   // wave-private rows

    h[tid] = 0; h[tid + 256] = 0;  // published by the prologue barrier

    // ---- A fragments: lane supplies row (row0+lr), k = s*16 + hb*8 + j.
    f16x8 ah[4], al[4];
    float xsq = 0.f;
    {
        const float* xr = x + (size_t)(row0 + lr) * D + hb * 8;
#pragma unroll
        for (int s = 0; s < 4; ++s) {
            float4 f0 = *(const float4*)(xr + s * 16);
            float4 f1 = *(const float4*)(xr + s * 16 + 4);
            float f[8] = {f0.x, f0.y, f0.z, f0.w, f1.x, f1.y, f1.z, f1.w};
#pragma unroll
            for (int j = 0; j < 8; ++j) {
                xsq = fmaf(f[j], f[j], xsq);
                _Float16 hv = (_Float16)f[j];
                ah[s][j] = hv;
                al[s][j] = (_Float16)(f[j] - (float)hv);
            }
        }
    }

    float    best[16];
    unsigned packlo = 0u, packhi = 0u;   // 4-bit best-tile (tt) per acc reg
#pragma unroll
    for (int r = 0; r < 16; ++r) best[r] = 3.0e38f;

    const f16x8* __restrict__ efv = (const f16x8*)ef;
    const int f0 = 2 * w;                // this wave's staging fragments

    // ---- prologue: stage tile 0 --------------------------------------------
    ebuf[0][f0 + 0][l] = efv[(f0 + 0) * 64 + l];
    ebuf[0][f0 + 1][l] = efv[(f0 + 1) * 64 + l];
    __syncthreads();

    int cur = 0;
#pragma unroll 2
    for (int tt = 0; tt < 16; ++tt) {
        // issue next tile's global loads first (latency hides under compute)
        f16x8 st0, st1;
        if (tt < 15) {
            st0 = efv[((tt + 1) * 8 + f0 + 0) * 64 + l];
            st1 = efv[((tt + 1) * 8 + f0 + 1) * 64 + l];
        }

        // compute tile tt from ebuf[cur]
        f32x16 acc = {};
#pragma unroll
        for (int s = 0; s < 4; ++s) {
            f16x8 bh = ebuf[cur][s * 2 + 0][l];
            f16x8 bl = ebuf[cur][s * 2 + 1][l];
            acc = __builtin_amdgcn_mfma_f32_32x32x16_f16(al[s], bh, acc, 0, 0, 0);
            acc = __builtin_amdgcn_mfma_f32_32x32x16_f16(ah[s], bl, acc, 0, 0, 0);
            acc = __builtin_amdgcn_mfma_f32_32x32x16_f16(ah[s], bh, acc, 0, 0, 0);
        }

        const float eq = e_sq[tt * 32 + lr];
#pragma unroll
        for (int r = 0; r < 16; ++r) {
            float sc = fmaf(-2.0f, acc[r], eq);
            bool better = sc < best[r];      // strict: earliest (smallest) tt
            best[r] = better ? sc : best[r]; // wins ties  == v_min_f32
            if (r < 8) {
                unsigned nb = (packlo & ~(15u << (4 * r)))
                            | ((unsigned)tt << (4 * r));
                packlo = better ? nb : packlo;
            } else {
                unsigned nb = (packhi & ~(15u << (4 * (r - 8))))
                            | ((unsigned)tt << (4 * (r - 8)));
                packhi = better ? nb : packhi;
            }
        }

        // write next tile into the other buffer; barrier publishes it and
        // retires everyone's reads of ebuf[cur] (overwritten 2 iters later)
        if (tt < 15) {
            ebuf[cur ^ 1][f0 + 0][l] = st0;
            ebuf[cur ^ 1][f0 + 1][l] = st1;
        }
        __syncthreads();
        cur ^= 1;
    }

    // ---- per-row argmin across the 32 lanes of each half: u64-key butterfly.
    float sum_best = 0.f;
#pragma unroll
    for (int r = 0; r < 16; ++r) {
        unsigned tt4 = ((r < 8) ? (packlo >> (4 * r))
                                : (packhi >> (4 * (r - 8)))) & 15u;
        int bk = ((int)tt4 << 5) | lr;
        unsigned sb = __float_as_uint(best[r]);
        sb ^= (unsigned)((int)sb >> 31) | 0x80000000u;   // monotone transform
        unsigned long long key =
            ((unsigned long long)sb << 32) | (unsigned)bk;
#pragma unroll
        for (int m = 16; m >= 1; m >>= 1) {
            unsigned long long o = __shfl_xor(key, m, 64);
            key = (o < key) ? o : key;
        }
        unsigned wb = (unsigned)(key >> 32);
        wb ^= ~(unsigned)((int)wb >> 31) | 0x80000000u;  // inverse transform
        sum_best += __uint_as_float(wb);
        if (lr == 0) {
            int ro = (r & 3) + 8 * (r >> 2) + 4 * hb;
            idx_s[w][ro] = (int)(key & 511u);
        }
    }
    // same-wave LDS write->read below: compiler inserts lgkmcnt, no barrier.

    // ---- loss: Sigma rows ||x||^2 (all 64 lane-halves) + Sigma best --------
    {
        float xs = xsq;
#pragma unroll
        for (int m = 32; m >= 1; m >>= 1) xs += __shfl_xor(xs, m, 64);
        float tb = sum_best + __shfl_xor(sum_best, 32, 64); // hb0 + hb1 sums
        if (l == 0)
            lparts[blockIdx.x * 4 + w] = xs + tb;           // plain store
    }

    // ---- indices + gather + out_q (wave-private, row-contiguous) -----------
    if (l < 32) {
        int bk = idx_s[w][l];
        out_idx[row0 + l] = (float)bk;
        idxN[row0 + l]    = bk;
    }
#pragma unroll
    for (int rr = 0; rr < 32; ++rr) {
        const int kk = idx_s[w][rr];
        out_q[(size_t)(row0 + rr) * D + l] = e_t[kk * D + l];
    }

    // ---- fused histogram: LDS count of this block's 128 rows, then sparse
    // global accumulate into hist64[blockIdx>>3][k] (replaces vq_hist).
    __syncthreads();                           // all idx_s final
    if (tid < 128)
        atomicAdd(&h[idx_s[tid >> 5][tid & 31]], 1);
    __syncthreads();
    int* hrow = hist64 + (blockIdx.x >> 3) * K;
    int v0 = h[tid], v1 = h[tid + 256];
    if (v0) atomicAdd(&hrow[tid], v0);
    if (v1) atomicAdd(&hrow[tid + 256], v1);
}

// ---------------- scatter: redundant scan + deterministic perm ---------------
// 64 blocks x 512.  Each block column-scans hist64 (64 iters) capturing its
// own base, Hillis-Steele over k for global offsets, then scatters its 1024
// rows via LDS counters.  Zero global atomics.  Block 0 publishes cnt[k].
__global__ __launch_bounds__(512)
void vq_scatter(const int* __restrict__ hist,  // [64][K]
                const int* __restrict__ idxN,  // [N]
                int* __restrict__ cnt,         // [K]
                int* __restrict__ perm)        // [N] (row<<9 | k), k-sorted
{
    __shared__ int s[K];

    const int t = threadIdx.x;            // 0..511
    const int b = blockIdx.x;

    int run = 0, mybase = 0;
    for (int b2 = 0; b2 < 64; ++b2) {     // column scan of hist[:, t]
        int h = hist[b2 * K + t];
        if (b2 == b) mybase = run;
        run += h;
    }
    if (b == 0) cnt[t] = run;             // total per bin

    s[t] = run;
    __syncthreads();
#pragma unroll
    for (int off = 1; off < K; off <<= 1) {   // inclusive scan of totals
        int v = (t >= off) ? s[t - off] : 0;
        __syncthreads();
        s[t] += v;
        __syncthreads();
    }
    const int offs = s[t] - run;          // exclusive prefix
    __syncthreads();
    s[t] = offs + mybase;                 // this block's start for bin t
    __syncthreads();

#pragma unroll
    for (int it = 0; it < 2; ++it) {
        int row = b * 1024 + it * 512 + t;
        int kk  = idxN[row];
        int pos = atomicAdd(&s[kk], 1);   // LDS atomic (block-local)
        perm[pos] = (row << 9) | kk;
    }
}

// ---------------- dw segmented reduce over k-sorted perm ---------------------
// 1024 blocks x 256 = 4096 waves; wave w owns perm chunk [16w, 16w+16).
// lane = d.  k is wave-uniform per entry -> flush only at run boundaries.
// 16 entries/wave doubles the wave pool (16/CU) vs r14's 32-entry shape —
// more TLP on an L2-gather-bound loop; flush count rises only ~2K.
__global__ __launch_bounds__(256, 2)
void vq_dwsum(const int* __restrict__ perm,  // [N] (row<<9 | k)
              const float* __restrict__ x,   // [N][D]
              float* __restrict__ dw_t)      // [K][D] accumulate
{
    const int w = (blockIdx.x * 256 + threadIdx.x) >> 6;  // 0..4095
    const int l = threadIdx.x & 63;

    int pv = 0;
    if (l < 16) pv = perm[w * 16 + l];

    float sum = 0.f;
    int kcur = -1;
#pragma unroll
    for (int e = 0; e < 16; ++e) {
        int pe  = __shfl(pv, e, 64);
        int kk  = pe & (K - 1);
        int row = pe >> 9;
        float xv = x[(size_t)row * D + l];
        if (kk != kcur) {                       // wave-uniform branch
            if (kcur >= 0) atomicAdd(&dw_t[kcur * D + l], sum);
            kcur = kk; sum = xv;
        } else {
            sum += xv;
        }
    }
    atomicAdd(&dw_t[kcur * D + l], sum);
}

// ---------------- finalize: scalars + hdw + new embeddings -------------------
// 128 blocks x 256.  Every block redundantly recomputes debias and the
// n-reduction from cnt (2KB, L2-resident).
__global__ __launch_bounds__(256)
void vq_final(const int*   __restrict__ cnt,     // [K]
              const float* __restrict__ lparts,  // [2048] per-wave loss
              const float* __restrict__ ema_csh, // [K]
              const int*   __restrict__ counter,
              const float* __restrict__ ema_dwh, // [D][K]
              const float* __restrict__ dw_t,    // [K][D]
              float* __restrict__ out_loss,
              float* __restrict__ out_perp,
              float* __restrict__ out_hcs,       // [K]
              float* __restrict__ out_nemb,      // [D][K]
              float* __restrict__ out_hdw)       // [D][K]
{
    __shared__ float s_red[4], s_red2[4];
    __shared__ float s_n;

    const int tid = threadIdx.x;
    const int b   = blockIdx.x;

    const int   cntr   = counter[0] + 1;
    const float debias = 1.0f - powf(DECAY, (float)cntr);

    const float c0 = (float)cnt[tid];
    const float c1 = (float)cnt[tid + 256];
    const float hid0 = ema_csh[tid] * DECAY + c0 * ONE_MINUS_DECAY;
    const float hid1 = ema_csh[tid + 256] * DECAY + c1 * ONE_MINUS_DECAY;
    const float upd0 = hid0 / debias;
    const float upd1 = hid1 / debias;

    float v = upd0 + upd1;
#pragma unroll
    for (int m = 32; m >= 1; m >>= 1) v += __shfl_xor(v, m, 64);
    if ((tid & 63) == 0) s_red[tid >> 6] = v;
    __syncthreads();
    if (tid == 0) s_n = s_red[0] + s_red[1] + s_red[2] + s_red[3];
    __syncthreads();
    const float n = s_n;

    const int i  = b * 256 + tid;          // 0..32767
    const int kk = i & (K - 1);
    const int d  = i >> 9;
    const float updk   = (b & 1) ? upd1 : upd0;
    const float stable = (updk + 1e-5f) / (n + (float)K * 1e-5f) * n;
    const float hdw = ema_dwh[i] * DECAY + dw_t[kk * D + d] * ONE_MINUS_DECAY;
    out_hdw[i]  = hdw;
    out_nemb[i] = (hdw / debias) / stable;

    if (b == 0) {
        out_hcs[tid]       = hid0;
        out_hcs[tid + 256] = hid1;

        const float inv = 1.0f / (float)NROWS;
        float p0 = c0 * inv, p1 = c1 * inv;
        float ve = p0 * logf(p0 + 1e-10f) + p1 * logf(p1 + 1e-10f);
        float lp = 0.f;
#pragma unroll
        for (int j = 0; j < 8; ++j) lp += lparts[tid + 256 * j];
#pragma unroll
        for (int m = 32; m >= 1; m >>= 1) {
            ve += __shfl_xor(ve, m, 64);
            lp += __shfl_xor(lp, m, 64);
        }
        __syncthreads();                    // safe re-use of s_red
        if ((tid & 63) == 0) { s_red[tid >> 6] = ve; s_red2[tid >> 6] = lp; }
        __syncthreads();
        if (tid == 0) {
            float e = s_red[0] + s_red[1] + s_red[2] + s_red[3];
            float L = s_red2[0] + s_red2[1] + s_red2[2] + s_red2[3];
            out_loss[0] = COMMIT * L / (float)((size_t)NROWS * D);
            out_perp[0] = expf(-e);
        }
    }
}

// ---------------- launch ------------------------------------------------------
extern "C" void kernel_launch(void* const* d_in, const int* in_sizes, int n_in,
                              void* d_out, int out_size, void* d_ws, size_t ws_size,
                              hipStream_t stream)
{
    const float* x_in    = (const float*)d_in[0];   // [64,32,32,64]
    const float* emb     = (const float*)d_in[1];   // [64,512]
    const float* ema_csh = (const float*)d_in[2];   // [512]
    const float* ema_dwh = (const float*)d_in[3];   // [64,512]
    const int*   counter = (const int*)d_in[4];     // [1]

    float* ws  = (float*)d_ws;
    float* out = (float*)d_out;

    vq_prep<<<128, 256, 0, stream>>>(emb, ws);

    vq_main<<<NROWS / 128, 256, 0, stream>>>(
        x_in, ws + WS_ESQ, ws + WS_ET, ws + WS_EF,
        out + OUT_Q, out + OUT_IDX,
        (int*)(ws + WS_IDX), (int*)(ws + WS_HIST), ws + WS_LPART);

    vq_scatter<<<64, 512, 0, stream>>>(
        (const int*)(ws + WS_HIST), (const int*)(ws + WS_IDX),
        (int*)(ws + WS_CNT), (int*)(ws + WS_PERM));

    vq_dwsum<<<1024, 256, 0, stream>>>(
        (const int*)(ws + WS_PERM), x_in, ws + WS_DWT);

    vq_final<<<128, 256, 0, stream>>>(
        (const int*)(ws + WS_CNT), ws + WS_LPART, ema_csh, counter,
        ema_dwh, ws + WS_DWT,
        out + OUT_LOSS, out + OUT_PERP, out + OUT_HCS,
        out + OUT_NEMB, out + OUT_HDW);
}

// Round 17
// 116.849 us; speedup vs baseline: 1.1603x; 1.0051x over previous
//
#include <hip/hip_runtime.h>
#include <math.h>

// Problem constants
#define D 64
#define K 512
#define NROWS 65536
#define DECAY 0.99f
#define ONE_MINUS_DECAY (1.0f - 0.99f)
#define COMMIT 0.25f

// ws layout (float offsets).  Pipeline: prep -> main -> scatter -> dwsum ->
// final.  r17 = r16 + TLP on the tail kernels: hist 64 -> 128 groups
// (scatter 128 blocks x 512, 1 row/thread) and dwsum 8 entries/wave
// (8192 waves).  vq_main byte-identical to r16/r14.
#define WS_DWT    0              // [K][D] = 32768 floats, dw accumulator (zeroed)
#define WS_CNT    32768          // [K] ints (written by scatter blk0)
#define WS_LPART  33280          // [2048] floats, per-wave loss (plain stores)
#define WS_ZERO4  8192           // float4 count zeroed by prep (= dw_t only)
#define WS_ESQ    35328          // [K]   ||e_k||^2
#define WS_ET     35840          // [K][D] fp32 embeddings transposed (gather)
#define WS_EF     68608          // f16 MFMA B-fragments: 8192 x 16B = 32768 floats
#define WS_IDX    101376         // [N] int indices
#define WS_HIST   166912         // [128][K] ints per-scatter-block histograms
#define WS_PERM   35840          // [N] int (row<<9 | k) — ALIASES ET+EF (dead
                                 // after vq_main; scatter runs later)
// high-water: (166912 + 65536)*4 = 929,792 B << 256 MiB ws (fill shows 256Mi)

// out layout (float offsets) — unchanged
#define OUT_Q     0
#define OUT_LOSS  4194304
#define OUT_PERP  4194305
#define OUT_IDX   4194306
#define OUT_NEMB  4259842
#define OUT_HCS   4292610
#define OUT_HDW   4293122

typedef _Float16 f16x8 __attribute__((ext_vector_type(8)));
typedef float    f32x16 __attribute__((ext_vector_type(16)));

// ---------------- prep: zero dw_t + hist128 + e_t + ||e||^2 + f16 fragments --
// B-fragment layout for v_mfma_f32_32x32x16_f16:
//   lane l supplies col = tile*32 + (l&31), k = (l>>5)*8 + j (j=0..7)
// fragment block index i = ((t*4 + s)*2 + h)*64 + l  (s=kstep, h=0 hi / 1 lo)
__global__ void vq_prep(const float* __restrict__ emb,  // [D][K]
                        float* __restrict__ ws)
{
    int i = blockIdx.x * 256 + threadIdx.x;   // 0..32767 (128 blocks)
    if (i < WS_ZERO4) {                       // zero dw_t
        ((float4*)ws)[i] = make_float4(0.f, 0.f, 0.f, 0.f);
    }
    int* hp = (int*)(ws + WS_HIST);           // zero hist128 (65536 ints)
    hp[i] = 0; hp[i + 32768] = 0;
    if (i < K * D) {                          // e_t[k][d] = emb[d][k]
        int k = i >> 6, d = i & 63;
        ws[WS_ET + i] = emb[d * K + k];
    }
    if (i < K) {                              // ||e_k||^2
        float s = 0.f;
        for (int d = 0; d < D; ++d) { float v = emb[d * K + i]; s += v * v; }
        ws[WS_ESQ + i] = s;
    }
    if (i < 8192) {                           // f16 hi/lo fragment buffer
        int l = i & 63, h = (i >> 6) & 1, s = (i >> 7) & 3, t = i >> 9;
        int col = t * 32 + (l & 31);
        int d0  = s * 16 + ((l >> 5) << 3);
        f16x8 frag;
#pragma unroll
        for (int j = 0; j < 8; ++j) {
            float v = emb[(d0 + j) * K + col];
            _Float16 hv = (_Float16)v;
            frag[j] = h ? (_Float16)(v - (float)hv) : hv;
        }
        ((f16x8*)(ws + WS_EF))[i] = frag;
    }
}

// ---------------- main: full-K/wave + LDS dbuf B + fused histogram -----------
// (byte-identical to r16's verified 117.4us vq_main except hist group >>2)
// 512 blocks x 4 waves; wave w owns rows blockIdx*128+w*32..+31, scans ALL
// 512 codes.  B-tile shared via 16KB LDS double buffer; 2 staging fragments
// live per wave (r15 showed 4-tile phases blow this to 8 -> VGPR 228).
// Argmin key = (monotone(score_bits)<<32) | k: u64 min == (min score, min k).
// Loss identity: sum((q-x)^2) = sum_rows(||x||^2 + best_score).
// C/D layout: col = lane&31, row = (reg&3) + 8*(reg>>2) + 4*(lane>>5).
__global__ __launch_bounds__(256, 4)
void vq_main(const float* __restrict__ x,     // [N][D]
             const float* __restrict__ e_sq,  // [K]
             const float* __restrict__ e_t,   // [K][D] fp32
             const float* __restrict__ ef,    // f16 fragment buffer
             float* __restrict__ out_q,       // [N][D]
             float* __restrict__ out_idx,     // [N] (float)
             int*   __restrict__ idxN,        // [N] int indices
             int*   __restrict__ hist128,     // [128][K] accumulate
             float* __restrict__ lparts)      // [2048] per-wave loss
{
    __shared__ f16x8 ebuf[2][8][64];          // 16 KB double-buffered B tile
    __shared__ int   idx_s[4][32];
    __shared__ int   h[K];

    const int tid  = threadIdx.x;
    const int w    = tid >> 6;
    const int l    = tid & 63;
    const int lr   = l & 31;       // A-row / B-col / C-col within tile
    const int hb   = l >> 5;       // k-group select
    const int row0 = blockIdx.x * 128 + w * 32;   // wave-private rows

    h[tid] = 0; h[tid + 256] = 0;  // published by the prologue barrier

    // ---- A fragments: lane supplies row (row0+lr), k = s*16 + hb*8 + j.
    f16x8 ah[4], al[4];
    float xsq = 0.f;
    {
        const float* xr = x + (size_t)(row0 + lr) * D + hb * 8;
#pragma unroll
        for (int s = 0; s < 4; ++s) {
            float4 f0 = *(const float4*)(xr + s * 16);
            float4 f1 = *(const float4*)(xr + s * 16 + 4);
            float f[8] = {f0.x, f0.y, f0.z, f0.w, f1.x, f1.y, f1.z, f1.w};
#pragma unroll
            for (int j = 0; j < 8; ++j) {
                xsq = fmaf(f[j], f[j], xsq);
                _Float16 hv = (_Float16)f[j];
                ah[s][j] = hv;
                al[s][j] = (_Float16)(f[j] - (float)hv);
            }
        }
    }

    float    best[16];
    unsigned packlo = 0u, packhi = 0u;   // 4-bit best-tile (tt) per acc reg
#pragma unroll
    for (int r = 0; r < 16; ++r) best[r] = 3.0e38f;

    const f16x8* __restrict__ efv = (const f16x8*)ef;
    const int f0 = 2 * w;                // this wave's staging fragments

    // ---- prologue: stage tile 0 --------------------------------------------
    ebuf[0][f0 + 0][l] = efv[(f0 + 0) * 64 + l];
    ebuf[0][f0 + 1][l] = efv[(f0 + 1) * 64 + l];
    __syncthreads();

    int cur = 0;
#pragma unroll 2
    for (int tt = 0; tt < 16; ++tt) {
        // issue next tile's global loads first (latency hides under compute)
        f16x8 st0, st1;
        if (tt < 15) {
            st0 = efv[((tt + 1) * 8 + f0 + 0) * 64 + l];
            st1 = efv[((tt + 1) * 8 + f0 + 1) * 64 + l];
        }

        // compute tile tt from ebuf[cur]
        f32x16 acc = {};
#pragma unroll
        for (int s = 0; s < 4; ++s) {
            f16x8 bh = ebuf[cur][s * 2 + 0][l];
            f16x8 bl = ebuf[cur][s * 2 + 1][l];
            acc = __builtin_amdgcn_mfma_f32_32x32x16_f16(al[s], bh, acc, 0, 0, 0);
            acc = __builtin_amdgcn_mfma_f32_32x32x16_f16(ah[s], bl, acc, 0, 0, 0);
            acc = __builtin_amdgcn_mfma_f32_32x32x16_f16(ah[s], bh, acc, 0, 0, 0);
        }

        const float eq = e_sq[tt * 32 + lr];
#pragma unroll
        for (int r = 0; r < 16; ++r) {
            float sc = fmaf(-2.0f, acc[r], eq);
            bool better = sc < best[r];      // strict: earliest (smallest) tt
            best[r] = better ? sc : best[r]; // wins ties  == v_min_f32
            if (r < 8) {
                unsigned nb = (packlo & ~(15u << (4 * r)))
                            | ((unsigned)tt << (4 * r));
                packlo = better ? nb : packlo;
            } else {
                unsigned nb = (packhi & ~(15u << (4 * (r - 8))))
                            | ((unsigned)tt << (4 * (r - 8)));
                packhi = better ? nb : packhi;
            }
        }

        // write next tile into the other buffer; barrier publishes it and
        // retires everyone's reads of ebuf[cur] (overwritten 2 iters later)
        if (tt < 15) {
            ebuf[cur ^ 1][f0 + 0][l] = st0;
            ebuf[cur ^ 1][f0 + 1][l] = st1;
        }
        __syncthreads();
        cur ^= 1;
    }

    // ---- per-row argmin across the 32 lanes of each half: u64-key butterfly.
    float sum_best = 0.f;
#pragma unroll
    for (int r = 0; r < 16; ++r) {
        unsigned tt4 = ((r < 8) ? (packlo >> (4 * r))
                                : (packhi >> (4 * (r - 8)))) & 15u;
        int bk = ((int)tt4 << 5) | lr;
        unsigned sb = __float_as_uint(best[r]);
        sb ^= (unsigned)((int)sb >> 31) | 0x80000000u;   // monotone transform
        unsigned long long key =
            ((unsigned long long)sb << 32) | (unsigned)bk;
#pragma unroll
        for (int m = 16; m >= 1; m >>= 1) {
            unsigned long long o = __shfl_xor(key, m, 64);
            key = (o < key) ? o : key;
        }
        unsigned wb = (unsigned)(key >> 32);
        wb ^= ~(unsigned)((int)wb >> 31) | 0x80000000u;  // inverse transform
        sum_best += __uint_as_float(wb);
        if (lr == 0) {
            int ro = (r & 3) + 8 * (r >> 2) + 4 * hb;
            idx_s[w][ro] = (int)(key & 511u);
        }
    }
    // same-wave LDS write->read below: compiler inserts lgkmcnt, no barrier.

    // ---- loss: Sigma rows ||x||^2 (all 64 lane-halves) + Sigma best --------
    {
        float xs = xsq;
#pragma unroll
        for (int m = 32; m >= 1; m >>= 1) xs += __shfl_xor(xs, m, 64);
        float tb = sum_best + __shfl_xor(sum_best, 32, 64); // hb0 + hb1 sums
        if (l == 0)
            lparts[blockIdx.x * 4 + w] = xs + tb;           // plain store
    }

    // ---- indices + gather + out_q (wave-private, row-contiguous) -----------
    if (l < 32) {
        int bk = idx_s[w][l];
        out_idx[row0 + l] = (float)bk;
        idxN[row0 + l]    = bk;
    }
#pragma unroll
    for (int rr = 0; rr < 32; ++rr) {
        const int kk = idx_s[w][rr];
        out_q[(size_t)(row0 + rr) * D + l] = e_t[kk * D + l];
    }

    // ---- fused histogram: LDS count of this block's 128 rows, then sparse
    // global accumulate into hist128[blockIdx>>2][k] (replaces vq_hist).
    __syncthreads();                           // all idx_s final
    if (tid < 128)
        atomicAdd(&h[idx_s[tid >> 5][tid & 31]], 1);
    __syncthreads();
    int* hrow = hist128 + (blockIdx.x >> 2) * K;
    int v0 = h[tid], v1 = h[tid + 256];
    if (v0) atomicAdd(&hrow[tid], v0);
    if (v1) atomicAdd(&hrow[tid + 256], v1);
}

// ---------------- scatter: redundant scan + deterministic perm ---------------
// 128 blocks x 512.  Each block column-scans hist128 (128 iters) capturing
// its own base, Hillis-Steele over k for global offsets, then scatters its
// 512 rows (1/thread) via LDS counters.  Zero global atomics.  Block 0
// publishes cnt[k].
__global__ __launch_bounds__(512)
void vq_scatter(const int* __restrict__ hist,  // [128][K]
                const int* __restrict__ idxN,  // [N]
                int* __restrict__ cnt,         // [K]
                int* __restrict__ perm)        // [N] (row<<9 | k), k-sorted
{
    __shared__ int s[K];

    const int t = threadIdx.x;            // 0..511
    const int b = blockIdx.x;

    int run = 0, mybase = 0;
    for (int b2 = 0; b2 < 128; ++b2) {    // column scan of hist[:, t]
        int h = hist[b2 * K + t];
        if (b2 == b) mybase = run;
        run += h;
    }
    if (b == 0) cnt[t] = run;             // total per bin

    s[t] = run;
    __syncthreads();
#pragma unroll
    for (int off = 1; off < K; off <<= 1) {   // inclusive scan of totals
        int v = (t >= off) ? s[t - off] : 0;
        __syncthreads();
        s[t] += v;
        __syncthreads();
    }
    const int offs = s[t] - run;          // exclusive prefix
    __syncthreads();
    s[t] = offs + mybase;                 // this block's start for bin t
    __syncthreads();

    {
        int row = b * 512 + t;
        int kk  = idxN[row];
        int pos = atomicAdd(&s[kk], 1);   // LDS atomic (block-local)
        perm[pos] = (row << 9) | kk;
    }
}

// ---------------- dw segmented reduce over k-sorted perm ---------------------
// 2048 blocks x 256 = 8192 waves; wave w owns perm chunk [8w, 8w+8).
// lane = d.  k is wave-uniform per entry -> flush only at run boundaries.
// perm runs average 128 long, so an 8-entry chunk has ~1 distinct k:
// flush count stays ~1/wave while the latency-hiding pool doubles vs r16.
__global__ __launch_bounds__(256, 2)
void vq_dwsum(const int* __restrict__ perm,  // [N] (row<<9 | k)
              const float* __restrict__ x,   // [N][D]
              float* __restrict__ dw_t)      // [K][D] accumulate
{
    const int w = (blockIdx.x * 256 + threadIdx.x) >> 6;  // 0..8191
    const int l = threadIdx.x & 63;

    int pv = 0;
    if (l < 8) pv = perm[w * 8 + l];

    float sum = 0.f;
    int kcur = -1;
#pragma unroll
    for (int e = 0; e < 8; ++e) {
        int pe  = __shfl(pv, e, 64);
        int kk  = pe & (K - 1);
        int row = pe >> 9;
        float xv = x[(size_t)row * D + l];
        if (kk != kcur) {                       // wave-uniform branch
            if (kcur >= 0) atomicAdd(&dw_t[kcur * D + l], sum);
            kcur = kk; sum = xv;
        } else {
            sum += xv;
        }
    }
    atomicAdd(&dw_t[kcur * D + l], sum);
}

// ---------------- finalize: scalars + hdw + new embeddings -------------------
// 128 blocks x 256.  Every block redundantly recomputes debias and the
// n-reduction from cnt (2KB, L2-resident).
__global__ __launch_bounds__(256)
void vq_final(const int*   __restrict__ cnt,     // [K]
              const float* __restrict__ lparts,  // [2048] per-wave loss
              const float* __restrict__ ema_csh, // [K]
              const int*   __restrict__ counter,
              const float* __restrict__ ema_dwh, // [D][K]
              const float* __restrict__ dw_t,    // [K][D]
              float* __restrict__ out_loss,
              float* __restrict__ out_perp,
              float* __restrict__ out_hcs,       // [K]
              float* __restrict__ out_nemb,      // [D][K]
              float* __restrict__ out_hdw)       // [D][K]
{
    __shared__ float s_red[4], s_red2[4];
    __shared__ float s_n;

    const int tid = threadIdx.x;
    const int b   = blockIdx.x;

    const int   cntr   = counter[0] + 1;
    const float debias = 1.0f - powf(DECAY, (float)cntr);

    const float c0 = (float)cnt[tid];
    const float c1 = (float)cnt[tid + 256];
    const float hid0 = ema_csh[tid] * DECAY + c0 * ONE_MINUS_DECAY;
    const float hid1 = ema_csh[tid + 256] * DECAY + c1 * ONE_MINUS_DECAY;
    const float upd0 = hid0 / debias;
    const float upd1 = hid1 / debias;

    float v = upd0 + upd1;
#pragma unroll
    for (int m = 32; m >= 1; m >>= 1) v += __shfl_xor(v, m, 64);
    if ((tid & 63) == 0) s_red[tid >> 6] = v;
    __syncthreads();
    if (tid == 0) s_n = s_red[0] + s_red[1] + s_red[2] + s_red[3];
    __syncthreads();
    const float n = s_n;

    const int i  = b * 256 + tid;          // 0..32767
    const int kk = i & (K - 1);
    const int d  = i >> 9;
    const float updk   = (b & 1) ? upd1 : upd0;
    const float stable = (updk + 1e-5f) / (n + (float)K * 1e-5f) * n;
    const float hdw = ema_dwh[i] * DECAY + dw_t[kk * D + d] * ONE_MINUS_DECAY;
    out_hdw[i]  = hdw;
    out_nemb[i] = (hdw / debias) / stable;

    if (b == 0) {
        out_hcs[tid]       = hid0;
        out_hcs[tid + 256] = hid1;

        const float inv = 1.0f / (float)NROWS;
        float p0 = c0 * inv, p1 = c1 * inv;
        float ve = p0 * logf(p0 + 1e-10f) + p1 * logf(p1 + 1e-10f);
        float lp = 0.f;
#pragma unroll
        for (int j = 0; j < 8; ++j) lp += lparts[tid + 256 * j];
#pragma unroll
        for (int m = 32; m >= 1; m >>= 1) {
            ve += __shfl_xor(ve, m, 64);
            lp += __shfl_xor(lp, m, 64);
        }
        __syncthreads();                    // safe re-use of s_red
        if ((tid & 63) == 0) { s_red[tid >> 6] = ve; s_red2[tid >> 6] = lp; }
        __syncthreads();
        if (tid == 0) {
            float e = s_red[0] + s_red[1] + s_red[2] + s_red[3];
            float L = s_red2[0] + s_red2[1] + s_red2[2] + s_red2[3];
            out_loss[0] = COMMIT * L / (float)((size_t)NROWS * D);
            out_perp[0] = expf(-e);
        }
    }
}

// ---------------- launch ------------------------------------------------------
extern "C" void kernel_launch(void* const* d_in, const int* in_sizes, int n_in,
                              void* d_out, int out_size, void* d_ws, size_t ws_size,
                              hipStream_t stream)
{
    const float* x_in    = (const float*)d_in[0];   // [64,32,32,64]
    const float* emb     = (const float*)d_in[1];   // [64,512]
    const float* ema_csh = (const float*)d_in[2];   // [512]
    const float* ema_dwh = (const float*)d_in[3];   // [64,512]
    const int*   counter = (const int*)d_in[4];     // [1]

    float* ws  = (float*)d_ws;
    float* out = (float*)d_out;

    vq_prep<<<128, 256, 0, stream>>>(emb, ws);

    vq_main<<<NROWS / 128, 256, 0, stream>>>(
        x_in, ws + WS_ESQ, ws + WS_ET, ws + WS_EF,
        out + OUT_Q, out + OUT_IDX,
        (int*)(ws + WS_IDX), (int*)(ws + WS_HIST), ws + WS_LPART);

    vq_scatter<<<128, 512, 0, stream>>>(
        (const int*)(ws + WS_HIST), (const int*)(ws + WS_IDX),
        (int*)(ws + WS_CNT), (int*)(ws + WS_PERM));

    vq_dwsum<<<2048, 256, 0, stream>>>(
        (const int*)(ws + WS_PERM), x_in, ws + WS_DWT);

    vq_final<<<128, 256, 0, stream>>>(
        (const int*)(ws + WS_CNT), ws + WS_LPART, ema_csh, counter,
        ema_dwh, ws + WS_DWT,
        out + OUT_LOSS, out + OUT_PERP, out + OUT_HCS,
        out + OUT_NEMB, out + OUT_HDW);
}